// Round 11
// baseline (27.762 us; speedup 1.0000x reference)
//
#include <hip/hip_runtime.h>

typedef float  f32x4 __attribute__((ext_vector_type(4)));
typedef short  s16x8 __attribute__((ext_vector_type(8)));
typedef ushort u16x8 __attribute__((ext_vector_type(8)));

constexpr int D  = 128;
constexpr int K  = 512;
constexpr int O  = 256;
constexpr int NT = 256;
constexpr float NL2E = -1.44269504088896340736f;  // -log2(e)

__device__ __forceinline__ ushort f2bf(float f) {
    uint u = __builtin_bit_cast(uint, f);
    return (ushort)((u + 0x7FFFu + ((u >> 16) & 1u)) >> 16);
}
__device__ __forceinline__ float bf2f(ushort h) {
    return __builtin_bit_cast(float, ((uint)h) << 16);
}

// ================= prep: fragment-ordered bf16 operands + fused stats =================
// chunk layout: chunk c holds 64 lanes x 8 bf16 (16B/lane, contiguous 1KB).
// X/C: c = (panel16*4 + q)*64 + lane ; elem = src[panel*16 + (lane&15)][q*32 + (lane>>4)*8 + j]
// W:   c = (kslab32*16 + ot)*64 + lane; elem = w[ot*16 + (lane&15)][kslab*32 + (lane>>4)*8 + j]
__global__ __launch_bounds__(NT)
void rbf_prep(const float* __restrict__ x, const float* __restrict__ cen,
              const float* __restrict__ ls, const float* __restrict__ w,
              ushort* __restrict__ Xh, ushort* __restrict__ Xl,
              ushort* __restrict__ Ch, ushort* __restrict__ Cl,
              ushort* __restrict__ Wf, float* __restrict__ xs2,
              float2* __restrict__ ecs, int nxb, int ncb)
{
    __shared__ float red[4][16];
    const int b = blockIdx.x, t = threadIdx.x, lane = t & 63, wq = t >> 6;

    if (b < nxb + ncb) {
        const bool isX  = b < nxb;
        const int panel = isX ? b : (b - nxb);
        const float* src = isX ? x : cen;
        ushort* dh = isX ? Xh : Ch;
        ushort* dl = isX ? Xl : Cl;
        const int row = panel * 16 + (lane & 15);
        const int col = wq * 32 + (lane >> 4) * 8;
        const float* p = src + (size_t)row * D + col;
        float4 v0 = *(const float4*)p, v1 = *(const float4*)(p + 4);
        float f[8] = {v0.x, v0.y, v0.z, v0.w, v1.x, v1.y, v1.z, v1.w};
        u16x8 h, l;
        float s = 0.f;
#pragma unroll
        for (int j = 0; j < 8; ++j) {
            s = fmaf(f[j], f[j], s);
            ushort hb = f2bf(f[j]);
            h[j] = hb;
            l[j] = f2bf(f[j] - bf2f(hb));
        }
        const size_t c = ((size_t)panel * 4 + wq) * 64 + lane;
        *(u16x8*)&dh[c * 8] = h;
        *(u16x8*)&dl[c * 8] = l;
        s += __shfl_xor(s, 16);
        s += __shfl_xor(s, 32);
        if (lane < 16) red[wq][lane] = s;
        __syncthreads();
        if (t < 16) {
            float sum = red[0][t] + red[1][t] + red[2][t] + red[3][t];
            if (isX) {
                xs2[panel * 16 + t] = sum;
            } else {
                int k = panel * 16 + t;
                float e = __expf(2.0f * ls[k]);
                ecs[k] = make_float2(NL2E * e, NL2E * e * sum);
            }
        }
    } else {
        const int c0 = (b - nxb - ncb) * NT + t;
        const int ln = c0 & 63, ot = (c0 >> 6) & 15, ks = c0 >> 10;
        const int o  = ot * 16 + (ln & 15);
        const int kb = ks * 32 + (ln >> 4) * 8;
        const float* p = w + (size_t)o * K + kb;
        float4 v0 = *(const float4*)p, v1 = *(const float4*)(p + 4);
        u16x8 h;
        h[0] = f2bf(v0.x); h[1] = f2bf(v0.y); h[2] = f2bf(v0.z); h[3] = f2bf(v0.w);
        h[4] = f2bf(v1.x); h[5] = f2bf(v1.y); h[6] = f2bf(v1.z); h[7] = f2bf(v1.w);
        *(u16x8*)&Wf[(size_t)c0 * 8] = h;
    }
}

// ================= main: 32 rows/block (2 panels/wave), 8 waves, wave = K-eighth =================
// Every C/W fragment feeds TWO row panels -> C+W L2 stream halves vs round-10.
// All accumulator/fragment arrays use static indices only (rule #20): panels
// are NAMED A/B, never indexed by a runtime value.
constexpr int PP = 40;   // Ps row stride in ushorts

__global__ __launch_bounds__(512, 1)   // 1 block/CU (LDS 88KB); VGPR cap 256
void rbf_main2p(const ushort* __restrict__ Xh, const ushort* __restrict__ Xl,
                const ushort* __restrict__ Ch, const ushort* __restrict__ Cl,
                const ushort* __restrict__ Wf, const float* __restrict__ xs2,
                const float2* __restrict__ ecs, float* __restrict__ out, int N)
{
    __shared__ ushort PsA[8][16][PP];     // 10.2 KB
    __shared__ ushort PsB[8][16][PP];     // 10.2 KB
    __shared__ float  Acc[2][32][O + 4];  // 66.6 KB
    __shared__ float  Ls[8][32];          // 1 KB

    const int t = threadIdx.x, lane = t & 63, wv = t >> 6;   // wv 0..7
    const int l15 = lane & 15, l4 = lane >> 4;
    const int pan = blockIdx.x;            // 32-row panel index

    // X fragments for both 16-row panels (frag-ordered -> base + lane*16B)
    s16x8 xhA[4], xlA[4], xhB[4], xlB[4];
    {
        const size_t baseA = ((size_t)(pan * 2) * 4) * 64 + lane;
        const size_t baseB = ((size_t)(pan * 2 + 1) * 4) * 64 + lane;
#pragma unroll
        for (int q = 0; q < 4; ++q) {
            xhA[q] = *(const s16x8*)&Xh[(baseA + q * 64) * 8];
            xlA[q] = *(const s16x8*)&Xl[(baseA + q * 64) * 8];
            xhB[q] = *(const s16x8*)&Xh[(baseB + q * 64) * 8];
            xlB[q] = *(const s16x8*)&Xl[(baseB + q * 64) * 8];
        }
    }
    const float xs2A = xs2[pan * 32 + l15];
    const float xs2B = xs2[pan * 32 + 16 + l15];

    f32x4 oaccA[16], oaccB[16];
#pragma unroll
    for (int i = 0; i < 16; ++i) {
        oaccA[i] = (f32x4){0.f, 0.f, 0.f, 0.f};
        oaccB[i] = (f32x4){0.f, 0.f, 0.f, 0.f};
    }
    float LpA = 0.f, LpB = 0.f;

    const int kw = wv * 64;   // wave's kernel base (K-eighth)

#pragma unroll
    for (int s = 0; s < 2; ++s) {
        const int kslab = (kw >> 5) + s;
        const ushort* wbase = &Wf[(((size_t)kslab * 16) * 64 + lane) * 8];

        // GEMM1 (swapped: A=C, B=X) + exp2, two 16-kernel tiles; C frags reused by both panels
#pragma unroll
        for (int bt = 0; bt < 2; ++bt) {
            const size_t kt16 = (size_t)(kw >> 4) + s * 2 + bt;
            s16x8 ch[4], cl[4];
#pragma unroll
            for (int q = 0; q < 4; ++q) {
                const size_t cc = ((kt16 * 4 + q) * 64 + lane) * 8;
                ch[q] = *(const s16x8*)&Ch[cc];
                cl[q] = *(const s16x8*)&Cl[cc];
            }
            f32x4 gA = (f32x4){0.f,0.f,0.f,0.f};
            f32x4 gB = (f32x4){0.f,0.f,0.f,0.f};
#pragma unroll
            for (int q = 0; q < 4; ++q) {
                gA = __builtin_amdgcn_mfma_f32_16x16x32_bf16(ch[q], xhA[q], gA, 0, 0, 0);
                gB = __builtin_amdgcn_mfma_f32_16x16x32_bf16(ch[q], xhB[q], gB, 0, 0, 0);
            }
#pragma unroll
            for (int q = 0; q < 4; ++q) {
                gA = __builtin_amdgcn_mfma_f32_16x16x32_bf16(ch[q], xlA[q], gA, 0, 0, 0);
                gB = __builtin_amdgcn_mfma_f32_16x16x32_bf16(ch[q], xlB[q], gB, 0, 0, 0);
            }
#pragma unroll
            for (int q = 0; q < 4; ++q) {
                gA = __builtin_amdgcn_mfma_f32_16x16x32_bf16(cl[q], xhA[q], gA, 0, 0, 0);
                gB = __builtin_amdgcn_mfma_f32_16x16x32_bf16(cl[q], xhB[q], gB, 0, 0, 0);
            }

            const int kbase = kw + s * 32 + bt * 16 + l4 * 4;
            float4 e0 = *(const float4*)&ecs[kbase];
            float4 e1 = *(const float4*)&ecs[kbase + 2];
            // panel A
            {
                float p0 = exp2f(fmaf(e0.x, fmaf(-2.f, gA[0], xs2A), e0.y));
                float p1 = exp2f(fmaf(e0.z, fmaf(-2.f, gA[1], xs2A), e0.w));
                float p2 = exp2f(fmaf(e1.x, fmaf(-2.f, gA[2], xs2A), e1.y));
                float p3 = exp2f(fmaf(e1.z, fmaf(-2.f, gA[3], xs2A), e1.w));
                LpA += (p0 + p1) + (p2 + p3);
                uint u0 = (uint)f2bf(p0) | ((uint)f2bf(p1) << 16);
                uint u1 = (uint)f2bf(p2) | ((uint)f2bf(p3) << 16);
                *(uint2*)&PsA[wv][l15][bt * 16 + l4 * 4] = make_uint2(u0, u1);
            }
            // panel B
            {
                float p0 = exp2f(fmaf(e0.x, fmaf(-2.f, gB[0], xs2B), e0.y));
                float p1 = exp2f(fmaf(e0.z, fmaf(-2.f, gB[1], xs2B), e0.w));
                float p2 = exp2f(fmaf(e1.x, fmaf(-2.f, gB[2], xs2B), e1.y));
                float p3 = exp2f(fmaf(e1.z, fmaf(-2.f, gB[3], xs2B), e1.w));
                LpB += (p0 + p1) + (p2 + p3);
                uint u0 = (uint)f2bf(p0) | ((uint)f2bf(p1) << 16);
                uint u1 = (uint)f2bf(p2) | ((uint)f2bf(p3) << 16);
                *(uint2*)&PsB[wv][l15][bt * 16 + l4 * 4] = make_uint2(u0, u1);
            }
        }

        // wave-private transpose reads (same-wave DS order, no barrier)
        s16x8 paA = *(const s16x8*)&PsA[wv][l15][l4 * 8];
        s16x8 paB = *(const s16x8*)&PsB[wv][l15][l4 * 8];
        // GEMM2: each W fragment feeds both panels
#pragma unroll
        for (int ot = 0; ot < 16; ++ot) {
            s16x8 bfr = *(const s16x8*)&wbase[(size_t)ot * 64 * 8];
            oaccA[ot] = __builtin_amdgcn_mfma_f32_16x16x32_bf16(paA, bfr, oaccA[ot], 0, 0, 0);
            oaccB[ot] = __builtin_amdgcn_mfma_f32_16x16x32_bf16(paB, bfr, oaccB[ot], 0, 0, 0);
        }
    }

    // per-wave row sums (over its 64 kernels) for both panels
    {
        float vA = LpA, vB = LpB;
        vA += __shfl_xor(vA, 16);  vA += __shfl_xor(vA, 32);
        vB += __shfl_xor(vB, 16);  vB += __shfl_xor(vB, 32);
        if (lane < 16) {
            Ls[wv][lane]      = vA;
            Ls[wv][16 + lane] = vB;
        }
    }

    // ---- combine 8 wave partials into 2 buffers: static 4-stage tree ----
    if (wv < 2) {
#pragma unroll
        for (int ot = 0; ot < 16; ++ot)
#pragma unroll
            for (int r = 0; r < 4; ++r) {
                Acc[wv][l4 * 4 + r][ot * 16 + l15]      = oaccA[ot][r];
                Acc[wv][16 + l4 * 4 + r][ot * 16 + l15] = oaccB[ot][r];
            }
    }
    __syncthreads();
    if (wv == 2 || wv == 3) {
#pragma unroll
        for (int ot = 0; ot < 16; ++ot)
#pragma unroll
            for (int r = 0; r < 4; ++r) {
                Acc[wv - 2][l4 * 4 + r][ot * 16 + l15]      += oaccA[ot][r];
                Acc[wv - 2][16 + l4 * 4 + r][ot * 16 + l15] += oaccB[ot][r];
            }
    }
    __syncthreads();
    if (wv == 4 || wv == 5) {
#pragma unroll
        for (int ot = 0; ot < 16; ++ot)
#pragma unroll
            for (int r = 0; r < 4; ++r) {
                Acc[wv - 4][l4 * 4 + r][ot * 16 + l15]      += oaccA[ot][r];
                Acc[wv - 4][16 + l4 * 4 + r][ot * 16 + l15] += oaccB[ot][r];
            }
    }
    __syncthreads();
    if (wv >= 6) {
#pragma unroll
        for (int ot = 0; ot < 16; ++ot)
#pragma unroll
            for (int r = 0; r < 4; ++r) {
                Acc[wv - 6][l4 * 4 + r][ot * 16 + l15]      += oaccA[ot][r];
                Acc[wv - 6][16 + l4 * 4 + r][ot * 16 + l15] += oaccB[ot][r];
            }
    }
    __syncthreads();

    // ---- store: sum 2 buffers + normalize; 512 thr, each 16 floats of one row ----
    {
        const int n  = t >> 4;           // 0..31
        const int c0 = (t & 15) * 16;    // 0..240
        float inv = 1.0f / (Ls[0][n] + Ls[1][n] + Ls[2][n] + Ls[3][n] +
                            Ls[4][n] + Ls[5][n] + Ls[6][n] + Ls[7][n] + 1e-9f);
        float* po = &out[(size_t)(pan * 32 + n) * O + c0];
#pragma unroll
        for (int j = 0; j < 4; ++j) {
            float4 a = *(const float4*)&Acc[0][n][c0 + j * 4];
            float4 b = *(const float4*)&Acc[1][n][c0 + j * 4];
            float4 o;
            o.x = (a.x + b.x) * inv;
            o.y = (a.y + b.y) * inv;
            o.z = (a.z + b.z) * inv;
            o.w = (a.w + b.w) * inv;
            *(float4*)(po + j * 4) = o;
        }
    }
}

// ================= fallback (round-4 kernel, known-pass, no ws) =================
__global__ __launch_bounds__(NT, 2)
void rbf_fb(const float* __restrict__ x, const float* __restrict__ cen,
            const float* __restrict__ ls, const float* __restrict__ w,
            float* __restrict__ out)
{
    __shared__ ushort Ps2[2][4][16][PP];
    __shared__ float  Acc2[2][16][O + 4];
    __shared__ float  Ls2[4][16];
    const int t = threadIdx.x, lane = t & 63, wv = t >> 6;
    const int l15 = lane & 15, l4 = lane >> 4;
    const int nb = blockIdx.x * 16;

    s16x8 xh[4], xl[4];
    float sx = 0.f;
    {
        const float* xr = x + (size_t)(nb + l15) * D;
#pragma unroll
        for (int q = 0; q < 4; ++q) {
            float4 v0 = *(const float4*)(xr + q * 32 + l4 * 8);
            float4 v1 = *(const float4*)(xr + q * 32 + l4 * 8 + 4);
            float f[8] = {v0.x, v0.y, v0.z, v0.w, v1.x, v1.y, v1.z, v1.w};
            s16x8 hh, lo;
#pragma unroll
            for (int j = 0; j < 8; ++j) {
                sx = fmaf(f[j], f[j], sx);
                ushort hb = f2bf(f[j]);
                hh[j] = (short)hb; lo[j] = (short)f2bf(f[j] - bf2f(hb));
            }
            xh[q] = hh; xl[q] = lo;
        }
    }
    sx += __shfl_xor(sx, 16); sx += __shfl_xor(sx, 32);
    float xs2v[4];
#pragma unroll
    for (int r = 0; r < 4; ++r) xs2v[r] = __shfl(sx, l4 * 4 + r);

    f32x4 oacc[16];
#pragma unroll
    for (int ot = 0; ot < 16; ++ot) oacc[ot] = (f32x4){0.f,0.f,0.f,0.f};
    float Lp[4] = {0.f,0.f,0.f,0.f};
    const int kq = wv * (K / 4);

#pragma unroll
    for (int s = 0; s < 4; ++s) {
        const int k0 = kq + s * 32;
#pragma unroll
        for (int bt = 0; bt < 2; ++bt) {
            const int kk = k0 + bt * 16 + l15;
            const float* cr = cen + (size_t)kk * D;
            s16x8 ch[4], cl[4];
            float sc = 0.f;
#pragma unroll
            for (int q = 0; q < 4; ++q) {
                float4 v0 = *(const float4*)(cr + q * 32 + l4 * 8);
                float4 v1 = *(const float4*)(cr + q * 32 + l4 * 8 + 4);
                float f[8] = {v0.x, v0.y, v0.z, v0.w, v1.x, v1.y, v1.z, v1.w};
                s16x8 hh, lo;
#pragma unroll
                for (int j = 0; j < 8; ++j) {
                    sc = fmaf(f[j], f[j], sc);
                    ushort hb = f2bf(f[j]);
                    hh[j] = (short)hb; lo[j] = (short)f2bf(f[j] - bf2f(hb));
                }
                ch[q] = hh; cl[q] = lo;
            }
            sc += __shfl_xor(sc, 16); sc += __shfl_xor(sc, 32);
            float es_ = __expf(2.0f * ls[kk]);
            f32x4 ghh={0,0,0,0}, ghl={0,0,0,0}, glh={0,0,0,0};
#pragma unroll
            for (int q = 0; q < 4; ++q) {
                ghh = __builtin_amdgcn_mfma_f32_16x16x32_bf16(xh[q], ch[q], ghh, 0,0,0);
                ghl = __builtin_amdgcn_mfma_f32_16x16x32_bf16(xh[q], cl[q], ghl, 0,0,0);
                glh = __builtin_amdgcn_mfma_f32_16x16x32_bf16(xl[q], ch[q], glh, 0,0,0);
            }
            f32x4 gg = ghh + ghl + glh;
#pragma unroll
            for (int r = 0; r < 4; ++r) {
                float r2 = xs2v[r] + sc - 2.0f * gg[r];
                float ph = __expf(-es_ * r2);
                Lp[r] += ph;
                Ps2[s & 1][wv][l4 * 4 + r][bt * 16 + l15] = f2bf(ph);
            }
        }
        s16x8 pa = *(const s16x8*)&Ps2[s & 1][wv][l15][l4 * 8];
#pragma unroll
        for (int ot = 0; ot < 16; ++ot) {
            const float* wr = w + (size_t)(ot * 16 + l15) * K + k0;
            float4 v0 = *(const float4*)(wr + l4 * 8);
            float4 v1 = *(const float4*)(wr + l4 * 8 + 4);
            s16x8 bb;
            bb[0]=(short)f2bf(v0.x); bb[1]=(short)f2bf(v0.y); bb[2]=(short)f2bf(v0.z); bb[3]=(short)f2bf(v0.w);
            bb[4]=(short)f2bf(v1.x); bb[5]=(short)f2bf(v1.y); bb[6]=(short)f2bf(v1.z); bb[7]=(short)f2bf(v1.w);
            oacc[ot] = __builtin_amdgcn_mfma_f32_16x16x32_bf16(pa, bb, oacc[ot], 0,0,0);
        }
    }
#pragma unroll
    for (int r = 0; r < 4; ++r) {
        float v = Lp[r];
        v += __shfl_xor(v, 1); v += __shfl_xor(v, 2);
        v += __shfl_xor(v, 4); v += __shfl_xor(v, 8);
        if (l15 == 0) Ls2[wv][l4 * 4 + r] = v;
    }
    if (wv < 2) {
#pragma unroll
        for (int ot = 0; ot < 16; ++ot)
#pragma unroll
            for (int r = 0; r < 4; ++r)
                Acc2[wv][l4 * 4 + r][ot * 16 + l15] = oacc[ot][r];
    }
    __syncthreads();
    if (wv >= 2) {
#pragma unroll
        for (int ot = 0; ot < 16; ++ot)
#pragma unroll
            for (int r = 0; r < 4; ++r)
                Acc2[wv - 2][l4 * 4 + r][ot * 16 + l15] += oacc[ot][r];
    }
    __syncthreads();
#pragma unroll
    for (int rr = 0; rr < 4; ++rr) {
        const int n = wv * 4 + rr;
        float inv = 1.0f / (Ls2[0][n] + Ls2[1][n] + Ls2[2][n] + Ls2[3][n] + 1e-9f);
        float4 a0 = *(const float4*)&Acc2[0][n][lane * 4];
        float4 a1 = *(const float4*)&Acc2[1][n][lane * 4];
        float4 o4;
        o4.x = (a0.x + a1.x) * inv; o4.y = (a0.y + a1.y) * inv;
        o4.z = (a0.z + a1.z) * inv; o4.w = (a0.w + a1.w) * inv;
        *(float4*)&out[(size_t)(nb + n) * O + lane * 4] = o4;
    }
}

extern "C" void kernel_launch(void* const* d_in, const int* in_sizes, int n_in,
                              void* d_out, int out_size, void* d_ws, size_t ws_size,
                              hipStream_t stream) {
    const float* x   = (const float*)d_in[0];  // N x 128
    const float* cen = (const float*)d_in[1];  // 512 x 128
    const float* ls  = (const float*)d_in[2];  // 512
    const float* w   = (const float*)d_in[3];  // 256 x 512
    float* out = (float*)d_out;                // N x 256
    const int N = in_sizes[0] / D;             // 8192

    size_t oXh = 0;
    size_t oXl = oXh + (size_t)N * D * 2;
    size_t oCh = oXl + (size_t)N * D * 2;
    size_t oCl = oCh + (size_t)K * D * 2;
    size_t oWf = oCl + (size_t)K * D * 2;
    size_t oxs = oWf + (size_t)O * K * 2;
    size_t oec = oxs + (size_t)N * 4;
    size_t need = oec + (size_t)K * 8;

    if (ws_size < need || (N % 32) != 0) {
        dim3 grid(N / 16), block(NT);
        hipLaunchKernelGGL(rbf_fb, grid, block, 0, stream, x, cen, ls, w, out);
        return;
    }

    char* ws = (char*)d_ws;
    ushort* Xh = (ushort*)(ws + oXh);
    ushort* Xl = (ushort*)(ws + oXl);
    ushort* Ch = (ushort*)(ws + oCh);
    ushort* Cl = (ushort*)(ws + oCl);
    ushort* Wf = (ushort*)(ws + oWf);
    float*  xs2 = (float*)(ws + oxs);
    float2* ecs = (float2*)(ws + oec);

    const int nxb = N / 16;                    // X panels
    const int ncb = K / 16;                    // C panels
    const int nwb = (O * K / 8) / NT;          // W blocks
    dim3 pgrid(nxb + ncb + nwb), pblock(NT);
    hipLaunchKernelGGL(rbf_prep, pgrid, pblock, 0, stream,
                       x, cen, ls, w, Xh, Xl, Ch, Cl, Wf, xs2, ecs, nxb, ncb);

    dim3 grid(N / 32), block(512);
    hipLaunchKernelGGL(rbf_main2p, grid, block, 0, stream,
                       Xh, Xl, Ch, Cl, Wf, xs2, ecs, out, N);
}